// Round 1
// baseline (154.405 us; speedup 1.0000x reference)
//
#include <hip/hip_runtime.h>

#define PATCH_N 64
#define CH      4
#define PADDED  192
#define BATCH   512

// One thread computes 4 consecutive output pixels (one float4) of one row of
// one batch's 192x192 canvas. Gather formulation: for each channel, test
// whether this pixel falls inside the translated patch footprint and, if so,
// bilinearly sample the patch (zero outside patch bounds).
__global__ __launch_bounds__(256)
void reassemble_kernel(const float* __restrict__ patches,
                       const float* __restrict__ positions,
                       float* __restrict__ out)
{
    const int b = blockIdx.y;                               // batch
    const int g = blockIdx.x * 256 + threadIdx.x;           // float4 index in canvas [0, 9216)
    const int y  = g / (PADDED / 4);                        // row 0..191
    const int x0 = (g % (PADDED / 4)) * 4;                  // first col of this float4

    // positions layout: (B, 1, 2, C) -> flat b*8 + j*4 + c ; j=0 -> dx, j=1 -> dy
    const float* __restrict__ pos = positions + (size_t)b * (2 * CH);

    float acc[4] = {0.f, 0.f, 0.f, 0.f};
    const float fy_base = (float)y - 64.0f;                 // patch row coord before -dy

#pragma unroll
    for (int c = 0; c < CH; ++c) {
        const float dxc = pos[c];
        const float dyc = pos[CH + c];

        const float py = fy_base - dyc;                     // patch-space row
        if (py <= -1.0f || py >= 64.0f) continue;           // row outside footprint

        const float fpy = floorf(py);
        const int   iy0 = (int)fpy;
        const float wy1 = py - fpy;
        const float wy0 = 1.0f - wy1;
        const bool  r0ok = (iy0 >= 0);                      // iy0 <= 63 guaranteed (py < 64)
        const bool  r1ok = (iy0 + 1 <= PATCH_N - 1);        // iy1 >= 0 guaranteed (py > -1)

        const float* __restrict__ row0 =
            patches + (((size_t)b * PATCH_N + (r0ok ? iy0 : 0)) * PATCH_N) * CH + c;
        const float* __restrict__ row1 =
            patches + (((size_t)b * PATCH_N + (r1ok ? iy0 + 1 : 0)) * PATCH_N) * CH + c;

#pragma unroll
        for (int k = 0; k < 4; ++k) {
            const float px = (float)(x0 + k) - dxc - 64.0f; // patch-space col
            if (px <= -1.0f || px >= 64.0f) continue;       // col outside footprint

            const float fpx = floorf(px);
            const int   ix0 = (int)fpx;
            const float wx1 = px - fpx;
            const float wx0 = 1.0f - wx1;
            const bool  c0ok = (ix0 >= 0);
            const bool  c1ok = (ix0 + 1 <= PATCH_N - 1);

            const int o0 = (c0ok ? ix0 : 0) * CH;
            const int o1 = (c1ok ? ix0 + 1 : 0) * CH;

            const float v00 = (r0ok && c0ok) ? row0[o0] : 0.f;
            const float v01 = (r0ok && c1ok) ? row0[o1] : 0.f;
            const float v10 = (r1ok && c0ok) ? row1[o0] : 0.f;
            const float v11 = (r1ok && c1ok) ? row1[o1] : 0.f;

            acc[k] += wy0 * (wx0 * v00 + wx1 * v01)
                    + wy1 * (wx0 * v10 + wx1 * v11);
        }
    }

    float4 o;
    o.x = acc[0]; o.y = acc[1]; o.z = acc[2]; o.w = acc[3];
    *reinterpret_cast<float4*>(out + (size_t)b * PADDED * PADDED + (size_t)g * 4) = o;
}

extern "C" void kernel_launch(void* const* d_in, const int* in_sizes, int n_in,
                              void* d_out, int out_size, void* d_ws, size_t ws_size,
                              hipStream_t stream) {
    const float* patches   = (const float*)d_in[0];
    const float* positions = (const float*)d_in[1];
    float* out = (float*)d_out;

    // 9216 float4s per batch canvas / 256 threads = 36 blocks; y-dim = batch
    dim3 grid(36, BATCH);
    reassemble_kernel<<<grid, 256, 0, stream>>>(patches, positions, out);
}

// Round 2
// 122.852 us; speedup vs baseline: 1.2568x; 1.2568x over previous
//
#include <hip/hip_runtime.h>

#define PATCH_N 64
#define CH      4
#define PADDED  192
#define BATCH   512
#define PLANE   (PATCH_N * PATCH_N)      // 4096 floats per channel plane
#define NPIX    (PADDED * PADDED)        // 36864 output pixels per batch
#define THREADS 1024

// One block per batch. Stage the 64x64x4 patch into LDS (planar per-channel,
// 64 KB), then compute the 192x192 canvas from LDS. Each wave covers 64
// consecutive x of a single row (192 = 3*64), so the per-channel row test is
// wave-uniform. LDS reads are stride-1 across lanes (conflict-free).
// 64 KB LDS + 1024 threads -> 2 blocks/CU = 32 waves/CU (full occupancy).
__global__ __launch_bounds__(THREADS, 8)
void reassemble_lds(const float* __restrict__ patches,
                    const float* __restrict__ positions,
                    float* __restrict__ out)
{
    __shared__ float lds[CH * PLANE];    // [c][iy*64+ix], 64 KB

    const int b   = blockIdx.x;
    const int tid = threadIdx.x;

    // ---- stage: 4096 pixel-float4s -> planar LDS (coalesced 16B loads) ----
    const float4* __restrict__ p4 =
        reinterpret_cast<const float4*>(patches + (size_t)b * PLANE * CH);
#pragma unroll
    for (int i = 0; i < PLANE / THREADS; ++i) {          // 4 iters
        const int idx = i * THREADS + tid;
        const float4 v = p4[idx];
        lds[0 * PLANE + idx] = v.x;
        lds[1 * PLANE + idx] = v.y;
        lds[2 * PLANE + idx] = v.z;
        lds[3 * PLANE + idx] = v.w;
    }

    // positions: (B,1,2,C) -> b*8 + j*4 + c ; j=0 dx, j=1 dy (block-uniform)
    const float* __restrict__ pos = positions + (size_t)b * (2 * CH);
    float dx[CH], dy[CH];
#pragma unroll
    for (int c = 0; c < CH; ++c) { dx[c] = pos[c]; dy[c] = pos[CH + c]; }

    __syncthreads();

    const int lane = tid & 63;
    const int wid  = tid >> 6;                           // 0..15
    float* __restrict__ outb = out + (size_t)b * NPIX;

#pragma unroll 4
    for (int it = 0; it < NPIX / THREADS; ++it) {        // 36 iters
        const int chunk = it * 16 + wid;                 // 0..575 (wave-uniform)
        const int y     = chunk / 3;                     // row (wave-uniform)
        const int xs    = chunk - y * 3;                 // 0..2
        const int x     = xs * 64 + lane;                // col (lane-consecutive)

        const float fy = (float)y - 64.0f;
        const float fx = (float)x - 64.0f;
        float acc = 0.0f;

#pragma unroll
        for (int c = 0; c < CH; ++c) {
            const float py = fy - dy[c];                 // wave-uniform
            if (py <= -1.0f || py >= 64.0f) continue;    // uniform skip

            const float fpy = floorf(py);
            int   iy0 = (int)fpy;
            float wy1 = py - fpy;
            float wy0 = 1.0f - wy1;
            int   iy1 = iy0 + 1;
            if (iy0 < 0)  { iy0 = 0;  wy0 = 0.0f; }      // top edge: v0* = 0
            if (iy1 > 63) { iy1 = 63; wy1 = 0.0f; }      // bottom edge: v1* = 0

            const float px = fx - dx[c];
            const bool  valid = (px > -1.0f) && (px < 64.0f);

            const float fpx = floorf(px);
            int   ix0 = (int)fpx;
            float wx1 = px - fpx;
            float wx0 = 1.0f - wx1;
            int   ix1 = ix0 + 1;
            if (ix0 < 0)  { ix0 = 0;  wx0 = 0.0f; }      // left edge
            if (ix1 > 63) { ix1 = 63; wx1 = 0.0f; }      // right edge
            ix0 = min(ix0, 63);                          // clamp far-OOB lanes
            ix1 = max(ix1, 0);                           // (masked by `valid`)

            const float* __restrict__ plane = lds + c * PLANE;
            const float v00 = plane[iy0 * PATCH_N + ix0];
            const float v01 = plane[iy0 * PATCH_N + ix1];
            const float v10 = plane[iy1 * PATCH_N + ix0];
            const float v11 = plane[iy1 * PATCH_N + ix1];

            const float contrib = wy0 * (wx0 * v00 + wx1 * v01)
                                + wy1 * (wx0 * v10 + wx1 * v11);
            acc += valid ? contrib : 0.0f;
        }

        outb[y * PADDED + x] = acc;                      // 256B/wave coalesced
    }
}

extern "C" void kernel_launch(void* const* d_in, const int* in_sizes, int n_in,
                              void* d_out, int out_size, void* d_ws, size_t ws_size,
                              hipStream_t stream) {
    const float* patches   = (const float*)d_in[0];
    const float* positions = (const float*)d_in[1];
    float* out = (float*)d_out;

    reassemble_lds<<<dim3(BATCH), THREADS, 0, stream>>>(patches, positions, out);
}

// Round 3
// 108.676 us; speedup vs baseline: 1.4208x; 1.1304x over previous
//
#include <hip/hip_runtime.h>

#define PATCH_N 64
#define CH      4
#define PADDED  192
#define BATCH   512
#define PLANE   (PATCH_N * PATCH_N)      // 4096 floats per channel plane
#define THREADS 1024

// One block per batch. Patch staged planar in exactly 64 KB LDS.
// Core insight: x,y are integers, so bilinear fractional weights are
// per-channel constants; the op is a constant-integer-shift 2x2 stencil.
// Per (channel, x-chunk) the column byte-offsets and validity-masked
// x-weights are loop-invariant -> precomputed in registers. Inner loop is
// 4 ds_read_b32 + 6 FMA per (channel, chunk). All clamped addresses stay
// inside initialized LDS; invalid taps get exact-0.0f weights.
__global__ __launch_bounds__(THREADS, 4)
void reassemble_u(const float* __restrict__ patches,
                  const float* __restrict__ positions,
                  float* __restrict__ out)
{
    __shared__ float lds[CH * PLANE];    // 64 KB, planar [c][iy*64+ix]

    const int b   = blockIdx.x;
    const int tid = threadIdx.x;

    // ---- stage: interleaved float4 -> planar LDS (stride-1 lanes, no conflicts)
    const float4* __restrict__ p4 =
        reinterpret_cast<const float4*>(patches + (size_t)b * PLANE * CH);
#pragma unroll
    for (int i = 0; i < PLANE / THREADS; ++i) {          // 4 iters
        const int idx = i * THREADS + tid;
        const float4 v = p4[idx];
        lds[0 * PLANE + idx] = v.x;
        lds[1 * PLANE + idx] = v.y;
        lds[2 * PLANE + idx] = v.z;
        lds[3 * PLANE + idx] = v.w;
    }

    // ---- per-channel constants (block-uniform): integer shift + frac weights
    const float* __restrict__ pos = positions + (size_t)b * 8;  // (1,2,C)
    int   sx[CH], sy[CH];
    float wx0[CH], wx1[CH], wy0[CH], wy1[CH];
#pragma unroll
    for (int c = 0; c < CH; ++c) {
        const float tx  = 64.0f + pos[c];        // dx
        const float sxf = ceilf(tx);
        sx[c]  = (int)sxf;
        wx1[c] = sxf - tx;
        wx0[c] = 1.0f - wx1[c];
        const float ty  = 64.0f + pos[CH + c];   // dy
        const float syf = ceilf(ty);
        sy[c]  = (int)syf;
        wy1[c] = syf - ty;
        wy0[c] = 1.0f - wy1[c];
    }

    const int lane = tid & 63;
    const int wid  = tid >> 6;                   // 0..15

    // ---- per-lane loop-invariants: 12 x {2 clamped byte offsets, 2 masked wx}
    int   pb0[CH][3], pb1[CH][3];
    float u0[CH][3],  u1[CH][3];
#pragma unroll
    for (int c = 0; c < CH; ++c) {
#pragma unroll
        for (int xs = 0; xs < 3; ++xs) {
            const int j0 = xs * 64 + lane - sx[c];          // column ix0
            const int a0 = min(max(j0, 0), 63);             // in-bounds addr
            const int a1 = min(max(j0 + 1, 0), 63);
            pb0[c][xs] = (c * PLANE + a0) * 4;              // byte offset in plane space
            pb1[c][xs] = (c * PLANE + a1) * 4;
            u0[c][xs] = ((unsigned)j0        < 64u) ? wx0[c] : 0.0f;
            u1[c][xs] = ((unsigned)(j0 + 1)  < 64u) ? wx1[c] : 0.0f;
        }
    }

    __syncthreads();

    const char* __restrict__ ldsb = reinterpret_cast<const char*>(lds);
    float* __restrict__ outb = out + (size_t)b * PADDED * PADDED;

#pragma unroll 2
    for (int it = 0; it < PADDED / 16; ++it) {   // 12 rows per wave, round-robin
        const int y = it * 16 + wid;             // wave-uniform row
        float acc0 = 0.f, acc1 = 0.f, acc2 = 0.f;

#pragma unroll
        for (int c = 0; c < CH; ++c) {
            const int iy0 = y - sy[c];
            if ((unsigned)(iy0 + 1) > 64u) continue;        // wave-uniform skip

            const int   r0b  = max(iy0, 0)      * (PATCH_N * 4);  // row byte offsets
            const int   r1b  = min(iy0 + 1, 63) * (PATCH_N * 4);
            const float wy0l = (iy0 >= 0) ? wy0[c] : 0.0f;        // top-edge mask
            const float wy1l = (iy0 <= 62) ? wy1[c] : 0.0f;       // bottom-edge mask

#define XS_BODY(XS, ACC)                                                        \
            {                                                                   \
                const float v00 = *reinterpret_cast<const float*>(ldsb + r0b + pb0[c][XS]); \
                const float v01 = *reinterpret_cast<const float*>(ldsb + r0b + pb1[c][XS]); \
                const float v10 = *reinterpret_cast<const float*>(ldsb + r1b + pb0[c][XS]); \
                const float v11 = *reinterpret_cast<const float*>(ldsb + r1b + pb1[c][XS]); \
                float h0 = u0[c][XS] * v00;                                     \
                h0 = fmaf(u1[c][XS], v01, h0);                                  \
                ACC = fmaf(wy0l, h0, ACC);                                      \
                float h1 = u0[c][XS] * v10;                                     \
                h1 = fmaf(u1[c][XS], v11, h1);                                  \
                ACC = fmaf(wy1l, h1, ACC);                                      \
            }
            XS_BODY(0, acc0)
            XS_BODY(1, acc1)
            XS_BODY(2, acc2)
#undef XS_BODY
        }

        const int o = y * PADDED + lane;
        __builtin_nontemporal_store(acc0, &outb[o]);
        __builtin_nontemporal_store(acc1, &outb[o + 64]);
        __builtin_nontemporal_store(acc2, &outb[o + 128]);
    }
}

extern "C" void kernel_launch(void* const* d_in, const int* in_sizes, int n_in,
                              void* d_out, int out_size, void* d_ws, size_t ws_size,
                              hipStream_t stream) {
    const float* patches   = (const float*)d_in[0];
    const float* positions = (const float*)d_in[1];
    float* out = (float*)d_out;

    reassemble_u<<<dim3(BATCH), THREADS, 0, stream>>>(patches, positions, out);
}